// Round 1
// baseline (1164.143 us; speedup 1.0000x reference)
//
#include <hip/hip_runtime.h>
#include <hip/hip_bf16.h>

#define NNODES 12000
#define NEDGES 384000
#define NETOT  (NEDGES + NNODES)   /* 396000 incl self-loops */
#define FIN    4
#define FHID   50
#define FOUT   1433
#define KP     1440                /* FOUT padded to multiple of 32 */
#define MP     12032               /* NNODES padded to multiple of 256 */
#define GT     (MP / 256)          /* 47 tiles of 256 */
#define GTRI   (GT * (GT + 1) / 2) /* 1128 upper-triangle tiles */
#define NEG_SLOPE 0.2f

typedef __hip_bfloat16 bf16_t;
typedef __bf16 bf16x8 __attribute__((ext_vector_type(8)));
typedef float f32x4 __attribute__((ext_vector_type(4)));
typedef float f32x2 __attribute__((ext_vector_type(2)));

__device__ __forceinline__ float  b2f(bf16_t h) { return __bfloat162float(h); }
__device__ __forceinline__ bf16_t f2b(float f)  { return __float2bfloat16(f); }
__device__ __forceinline__ unsigned short f2bu(float f) { bf16_t h = f2b(f); return *(unsigned short*)&h; }

// ---------------- init: deg=1 (self loop), zero pad rows of h2 (bf16) ----------------
__global__ void k_init(int* __restrict__ deg, bf16_t* __restrict__ h2) {
    int i = blockIdx.x * blockDim.x + threadIdx.x;
    int stride = gridDim.x * blockDim.x;
    for (int v = i; v < NNODES; v += stride) deg[v] = 1;
    const size_t padN = (size_t)(MP - NNODES) * KP;
    for (size_t t = i; t < padN; t += stride) h2[(size_t)NNODES * KP + t] = f2b(0.f);
}

// ---------------- count real edges by dst ----------------
__global__ void k_count(const int* __restrict__ ei, int* __restrict__ deg) {
    int i = blockIdx.x * blockDim.x + threadIdx.x;
    if (i < NEDGES) atomicAdd(&deg[ei[NEDGES + i]], 1);
}

// ---------------- single-block shfl exclusive scan -> rowptr[N+1] + cursor[N] ----------------
// 12 elems/thread blocked; wave shfl-scan; 16-wave LDS combine; 2 barriers total.
__global__ __launch_bounds__(1024) void k_scan(const int* __restrict__ deg,
                                               int* __restrict__ rowptr,
                                               int* __restrict__ cursor) {
    __shared__ int wsum[16];
    const int tid = threadIdx.x, lane = tid & 63, wv = tid >> 6;
    const int base = tid * 12;
    int pref[12];
    int s = 0;
#pragma unroll
    for (int u = 0; u < 12; ++u) {
        int idx = base + u;
        int d = (idx < NNODES) ? deg[idx] : 0;
        pref[u] = s;
        s += d;
    }
    int sc = s;   // inclusive wave scan of per-thread sums
#pragma unroll
    for (int o = 1; o < 64; o <<= 1) {
        int t2 = __shfl_up(sc, o, 64);
        if (lane >= o) sc += t2;
    }
    if (lane == 63) wsum[wv] = sc;
    __syncthreads();
    if (wv == 0 && lane < 16) {
        int mine = wsum[lane];
        int scw = mine;
#pragma unroll
        for (int o = 1; o < 16; o <<= 1) {
            int t3 = __shfl_up(scw, o, 64);
            if (lane >= o) scw += t3;
        }
        wsum[lane] = scw - mine;   // exclusive wave prefix
    }
    __syncthreads();
    const int pre = wsum[wv] + (sc - s);   // exclusive prefix of this thread
#pragma unroll
    for (int u = 0; u < 12; ++u) {
        int idx = base + u;
        if (idx < NNODES) {
            int p = pre + pref[u];
            rowptr[idx] = p;
            cursor[idx] = p;
        }
    }
    if (tid == 1023) rowptr[NNODES] = pre + s;   // == NETOT
}

// ---------------- fill CSR src lists (incl self loops) + edge passthrough ----------------
__global__ void k_fill(const int* __restrict__ ei, int* __restrict__ cursor,
                       int* __restrict__ csrc, float* __restrict__ outbase) {
    int i = blockIdx.x * blockDim.x + threadIdx.x;
    if (i < NETOT) {
        int s, d;
        if (i < NEDGES) { s = ei[i]; d = ei[NEDGES + i]; }
        else            { s = d = i - NEDGES; }
        int pos = atomicAdd(&cursor[d], 1);
        csrc[pos] = s;
    }
    if (i < 2 * NEDGES)
        outbase[(size_t)NNODES * (size_t)NNODES + (size_t)i] = (float)ei[i];
}

// ---------------- layer1 linear: h1pre = x @ W1, al1/ar1 logit parts ----------------
__global__ __launch_bounds__(256) void k_linear1(
        const bf16_t* __restrict__ x, const bf16_t* __restrict__ W1,
        const bf16_t* __restrict__ as1, const bf16_t* __restrict__ ad1,
        float* __restrict__ h1pre, float* __restrict__ al, float* __restrict__ ar) {
    __shared__ float sW[FIN * FHID];
    __shared__ float sa[FHID], sdl[FHID];
    int tid = threadIdx.x;
    if (tid < FIN * FHID) sW[tid] = b2f(W1[tid]);
    if (tid < FHID) { sa[tid] = b2f(as1[tid]); sdl[tid] = b2f(ad1[tid]); }
    __syncthreads();
    int i = blockIdx.x * 256 + tid;
    if (i >= NNODES) return;
    float x0 = b2f(x[i * 4 + 0]), x1 = b2f(x[i * 4 + 1]);
    float x2 = b2f(x[i * 4 + 2]), x3 = b2f(x[i * 4 + 3]);
    float hal = 0.f, har = 0.f;
    for (int j = 0; j < FHID; ++j) {
        float h = x0 * sW[j] + x1 * sW[FHID + j] + x2 * sW[2 * FHID + j] + x3 * sW[3 * FHID + j];
        h1pre[(size_t)i * FHID + j] = h;
        hal += h * sa[j];
        har += h * sdl[j];
    }
    al[i] = hal; ar[i] = har;
}

// ---------------- layer1 softmax-aggregate: wave-per-node, no max pass, shfl broadcast ----------------
__global__ __launch_bounds__(256) void k_agg1(
        const float* __restrict__ h1pre, const float* __restrict__ al, const float* __restrict__ ar,
        const int* __restrict__ rowptr, const int* __restrict__ csrc,
        const bf16_t* __restrict__ b1, float* __restrict__ h1) {
    const int wv = threadIdx.x >> 6, lane = threadIdx.x & 63;
    const int v = blockIdx.x * 4 + wv;        // NNODES % 4 == 0
    const int s0 = rowptr[v], s1 = rowptr[v + 1];
    const float arv = ar[v];
    float acc = 0.f, ssum = 0.f;
    for (int base = s0; base < s1; base += 64) {
        int e = base + lane;
        float w = 0.f; int si = 0;
        if (e < s1) {
            si = csrc[e];
            float l = al[si] + arv;
            l = l > 0.f ? l : NEG_SLOPE * l;
            w = __expf(l);                     // softmax is shift-invariant; |l| small
        }
        ssum += w;
        int cnt = min(64, s1 - base);
#pragma unroll 4
        for (int j = 0; j < cnt; ++j) {
            float wj = __shfl(w, j, 64);
            int   sj = __shfl(si, j, 64);
            if (lane < FHID) acc += wj * h1pre[(size_t)sj * FHID + lane];
        }
    }
#pragma unroll
    for (int o = 32; o; o >>= 1) ssum += __shfl_xor(ssum, o, 64);
    if (lane < FHID) {
        float o2 = acc / ssum + b2f(b1[lane]);
        h1[(size_t)v * FHID + lane] = fmaxf(o2, 0.f);
    }
}

// ---------------- layer2 linear: 4 nodes/block, h2pre (fp8 e4m3) = h1 @ W2, al2/ar2 ----------------
__global__ __launch_bounds__(256) void k_linear2(
        const float* __restrict__ h1, const bf16_t* __restrict__ W2,
        const bf16_t* __restrict__ as2, const bf16_t* __restrict__ ad2,
        unsigned char* __restrict__ h2pre, float* __restrict__ al2, float* __restrict__ ar2) {
    int v0 = blockIdx.x * 4, tid = threadIdx.x;
    __shared__ float sh[4][FHID];
    if (tid < 4 * FHID) sh[tid / FHID][tid % FHID] = h1[(size_t)v0 * FHID + tid];
    __syncthreads();
    float pal[4] = {0.f, 0.f, 0.f, 0.f}, par[4] = {0.f, 0.f, 0.f, 0.f};
#pragma unroll
    for (int i = 0; i < 3; ++i) {
        int f0 = i * 512 + 2 * tid;          // even feature index
        if (f0 < KP) {
            float d0[4] = {0.f, 0.f, 0.f, 0.f}, d1[4] = {0.f, 0.f, 0.f, 0.f};
            bool ok0 = f0 < FOUT, ok1 = f0 + 1 < FOUT;
            if (ok0) {
                int f1 = ok1 ? f0 + 1 : f0;  // safe aliased read when f0+1 OOB
#pragma unroll 10
                for (int k = 0; k < FHID; ++k) {
                    float w0 = b2f(W2[k * FOUT + f0]);
                    float w1 = b2f(W2[k * FOUT + f1]);
#pragma unroll
                    for (int c = 0; c < 4; ++c) {
                        d0[c] += sh[c][k] * w0;
                        d1[c] += sh[c][k] * w1;
                    }
                }
                if (!ok1) { d1[0] = d1[1] = d1[2] = d1[3] = 0.f; }
                float sa0 = b2f(as2[f0]), sd0 = b2f(ad2[f0]);
                float sa1 = ok1 ? b2f(as2[f0 + 1]) : 0.f;
                float sd1 = ok1 ? b2f(ad2[f0 + 1]) : 0.f;
#pragma unroll
                for (int c = 0; c < 4; ++c) {
                    pal[c] += d0[c] * sa0 + d1[c] * sa1;
                    par[c] += d0[c] * sd0 + d1[c] * sd1;
                }
            }
#pragma unroll
            for (int c = 0; c < 4; ++c) {
                int pk = __builtin_amdgcn_cvt_pk_fp8_f32(d0[c], d1[c], 0, false);
                *(unsigned short*)(h2pre + (size_t)(v0 + c) * KP + f0) = (unsigned short)pk;
            }
        }
    }
#pragma unroll
    for (int off = 32; off; off >>= 1)
#pragma unroll
        for (int c = 0; c < 4; ++c) {
            pal[c] += __shfl_xor(pal[c], off, 64);
            par[c] += __shfl_xor(par[c], off, 64);
        }
    __shared__ float rA[4][4], rB[4][4];
    int wave = tid >> 6, lane = tid & 63;
    if (lane == 0)
#pragma unroll
        for (int c = 0; c < 4; ++c) { rA[wave][c] = pal[c]; rB[wave][c] = par[c]; }
    __syncthreads();
    if (tid < 4) {
        al2[v0 + tid] = rA[0][tid] + rA[1][tid] + rA[2][tid] + rA[3][tid];
        ar2[v0 + tid] = rB[0][tid] + rB[1][tid] + rB[2][tid] + rB[3][tid];
    }
}

// ---------------- layer2 softmax-aggregate: fp8 gather, no max pass, bf16 h2 out ----------------
__global__ __launch_bounds__(256) void k_agg2(
        const unsigned char* __restrict__ h2pre, const float* __restrict__ al, const float* __restrict__ ar,
        const int* __restrict__ rowptr, const int* __restrict__ csrc,
        const bf16_t* __restrict__ bias2, bf16_t* __restrict__ h2) {
    int v = blockIdx.x, tid = threadIdx.x;
    int s0 = rowptr[v], s1 = rowptr[v + 1];
    float arv = ar[v];
    int wave = tid >> 6, lane = tid & 63;

    float acc[8] = {0.f, 0.f, 0.f, 0.f, 0.f, 0.f, 0.f, 0.f};
    float ssum = 0.f;
    __shared__ float sw[256];
    __shared__ int ssrc[256];
    __shared__ float red[4];
    const bool act = tid < (KP / 8);          // 180 lanes cover the 1440-B row
    for (int base = s0; base < s1; base += 256) {
        int e = base + tid;
        float w = 0.f; int si = 0;
        if (e < s1) {
            si = csrc[e];
            float l = al[si] + arv;
            l = l > 0.f ? l : NEG_SLOPE * l;
            w = __expf(l);                    // shift-invariant; |l| small
        }
        ssum += w;
        sw[tid] = w; ssrc[tid] = si;
        __syncthreads();
        int cnt = min(256, s1 - base);
        if (act) {
#pragma unroll 8
            for (int j = 0; j < cnt; ++j) {
                float wj = sw[j];
                const uint2* hp = (const uint2*)(h2pre + (size_t)ssrc[j] * KP);
                uint2 p = hp[tid];
                f32x2 e0 = __builtin_amdgcn_cvt_pk_f32_fp8(p.x, false);
                f32x2 e1 = __builtin_amdgcn_cvt_pk_f32_fp8(p.x, true);
                f32x2 e2 = __builtin_amdgcn_cvt_pk_f32_fp8(p.y, false);
                f32x2 e3 = __builtin_amdgcn_cvt_pk_f32_fp8(p.y, true);
                acc[0] += wj * e0.x; acc[1] += wj * e0.y;
                acc[2] += wj * e1.x; acc[3] += wj * e1.y;
                acc[4] += wj * e2.x; acc[5] += wj * e2.y;
                acc[6] += wj * e3.x; acc[7] += wj * e3.y;
            }
        }
        __syncthreads();
    }
#pragma unroll
    for (int off = 32; off; off >>= 1) ssum += __shfl_xor(ssum, off, 64);
    if (lane == 0) red[wave] = ssum;
    __syncthreads();
    float inv = 1.f / (red[0] + red[1] + red[2] + red[3]);

    if (act) {
        int fb = 8 * tid;
        unsigned short o[8];
#pragma unroll
        for (int t = 0; t < 8; ++t) {
            int f = fb + t;
            o[t] = f2bu((f < FOUT) ? fmaxf(acc[t] * inv + b2f(bias2[f]), 0.f) : 0.f);
        }
        uint4 pk;
        pk.x = (unsigned)o[0] | ((unsigned)o[1] << 16);
        pk.y = (unsigned)o[2] | ((unsigned)o[3] << 16);
        pk.z = (unsigned)o[4] | ((unsigned)o[5] << 16);
        pk.w = (unsigned)o[6] | ((unsigned)o[7] << 16);
        *(uint4*)(h2 + (size_t)v * KP + fb) = pk;
    }
}

// ---------------- final: out = sigmoid(H @ H^T) ----------------
// 256x256 tile, 8 waves (2Mx4N), BK=64 double-buffered 128KiB LDS, st_16x32
// swizzle (inverse-swizzled global source + swizzled ds_read), counted
// s_waitcnt vmcnt(8) across raw s_barriers (never drain-0 in the loop).
// K = 1440 = 22*64 + 32; the 32-wide tail reads fragments straight from
// global (H is L2/L3-resident) to avoid a second staging path.
__global__ __launch_bounds__(512, 2) void k_gemm_sig(const bf16_t* __restrict__ Hm,
                                                     float* __restrict__ out) {
    // decode linear tile id -> (by, bx) with bx >= by
    int t = blockIdx.x;
    int by = (int)((2 * GT + 1 - sqrtf((float)(2 * GT + 1) * (2 * GT + 1) - 8.0f * t)) * 0.5f);
    if (by < 0) by = 0;
    if (by > GT - 1) by = GT - 1;
    while (by + 1 < GT && (by + 1) * GT - ((by + 1) * by) / 2 <= t) ++by;
    while (by > 0 && by * GT - (by * (by - 1)) / 2 > t) --by;
    int bx = by + (t - (by * GT - (by * (by - 1)) / 2));

    __shared__ __align__(16) char ldsA[2 * 256 * 64 * 2];   // 64 KiB (2 slots)
    __shared__ __align__(16) char ldsB[2 * 256 * 64 * 2];   // 64 KiB

    const int tid  = threadIdx.x;
    const int wave = tid >> 6, lane = tid & 63;
    const int rowA0 = by * 256, rowB0 = bx * 256;

    // staging: LDS dest is linear (wave-uniform base + lane*16); the st_16x32
    // swizzle (byte ^= ((byte>>9)&1)<<5) is applied as its inverse on the
    // per-lane GLOBAL source so that swizzled ds_reads see logical data.
    const int phys  = wave * 1024 + lane * 16;               // within one 8KB round
    const int physL = phys ^ (((phys >> 9) & 1) << 5);
    const int srow  = physL >> 7;                            // 0..63
    const int scol  = (physL & 127) >> 1;                    // element 0..63
    const bf16_t* gA0 = Hm + (size_t)(rowA0 + srow) * KP + scol;
    const bf16_t* gB0 = Hm + (size_t)(rowB0 + srow) * KP + scol;

#define STAGE_TILE(slot_, kt_) do {                                            \
        char* la_ = ldsA + (slot_) * 32768 + wave * 1024;                      \
        char* lb_ = ldsB + (slot_) * 32768 + wave * 1024;                      \
        _Pragma("unroll")                                                      \
        for (int c_ = 0; c_ < 4; ++c_)                                         \
            __builtin_amdgcn_global_load_lds(                                  \
                (const __attribute__((address_space(1))) void*)(gA0 + (size_t)(c_ * 64) * KP + (kt_) * 64), \
                (__attribute__((address_space(3))) void*)(la_ + c_ * 8192), 16, 0, 0); \
        _Pragma("unroll")                                                      \
        for (int c_ = 0; c_ < 4; ++c_)                                         \
            __builtin_amdgcn_global_load_lds(                                  \
                (const __attribute__((address_space(1))) void*)(gB0 + (size_t)(c_ * 64) * KP + (kt_) * 64), \
                (__attribute__((address_space(3))) void*)(lb_ + c_ * 8192), 16, 0, 0); \
    } while (0)

    const int wr = wave >> 2, wc = wave & 3;    // 2M x 4N wave grid
    const int r = lane & 15, q = lane >> 4;
    const int swz = (r & 4) << 3;               // ((row>>2)&1)<<5, row&4 == r&4
    const int aBase = wr * 16384 + r * 128;     // row byte base in A slot
    const int bBase = wc * 8192  + r * 128;     // row byte base in B slot

    f32x4 acc[8][4] = {};

    STAGE_TILE(0, 0);
    for (int kt = 0; kt < 22; ++kt) {
        if (kt < 21) {
            STAGE_TILE((kt + 1) & 1, kt + 1);
            __builtin_amdgcn_sched_barrier(0);
            asm volatile("s_waitcnt vmcnt(8)" ::: "memory");   // tile kt landed; kt+1 in flight
        } else {
            __builtin_amdgcn_sched_barrier(0);
            asm volatile("s_waitcnt vmcnt(0)" ::: "memory");   // last tile: drain
        }
        __builtin_amdgcn_s_barrier();
        __builtin_amdgcn_sched_barrier(0);
        const char* Ab = ldsA + (kt & 1) * 32768;
        const char* Bb = ldsB + (kt & 1) * 32768;
#pragma unroll
        for (int ks = 0; ks < 2; ++ks) {
            const int cb = ks * 64 + ((q * 16) ^ swz);
            bf16x8 af[8], bfr[4];
#pragma unroll
            for (int mi = 0; mi < 8; ++mi)
                af[mi] = *(const bf16x8*)(Ab + aBase + mi * 2048 + cb);
#pragma unroll
            for (int ni = 0; ni < 4; ++ni)
                bfr[ni] = *(const bf16x8*)(Bb + bBase + ni * 2048 + cb);
#pragma unroll
            for (int mi = 0; mi < 8; ++mi)
#pragma unroll
                for (int ni = 0; ni < 4; ++ni)
                    acc[mi][ni] = __builtin_amdgcn_mfma_f32_16x16x32_bf16(af[mi], bfr[ni], acc[mi][ni], 0, 0, 0);
        }
        __builtin_amdgcn_sched_barrier(0);
        __builtin_amdgcn_s_barrier();
        __builtin_amdgcn_sched_barrier(0);
    }
#undef STAGE_TILE

    // K tail: columns 1408..1439, fragments straight from global
    {
        bf16x8 at[8], bt[4];
#pragma unroll
        for (int mi = 0; mi < 8; ++mi)
            at[mi] = *(const bf16x8*)(Hm + (size_t)(rowA0 + wr * 128 + mi * 16 + r) * KP + 1408 + q * 8);
#pragma unroll
        for (int ni = 0; ni < 4; ++ni)
            bt[ni] = *(const bf16x8*)(Hm + (size_t)(rowB0 + wc * 64 + ni * 16 + r) * KP + 1408 + q * 8);
#pragma unroll
        for (int mi = 0; mi < 8; ++mi)
#pragma unroll
            for (int ni = 0; ni < 4; ++ni)
                acc[mi][ni] = __builtin_amdgcn_mfma_f32_16x16x32_bf16(at[mi], bt[ni], acc[mi][ni], 0, 0, 0);
    }

    // epilogue. C/D layout: col=lane&15, row=(lane>>4)*4+reg. NNODES%4==0.
#pragma unroll
    for (int mi = 0; mi < 8; ++mi) {
        const int row0 = rowA0 + wr * 128 + mi * 16 + q * 4;
#pragma unroll
        for (int ni = 0; ni < 4; ++ni) {
            const int col = rowB0 + wc * 64 + ni * 16 + r;
            if (col < NNODES && row0 < NNODES) {
                f32x4 s;
#pragma unroll
                for (int r2 = 0; r2 < 4; ++r2)
                    s[r2] = 1.f / (1.f + __expf(-acc[mi][ni][r2]));
#pragma unroll
                for (int r2 = 0; r2 < 4; ++r2)
                    out[(size_t)(row0 + r2) * NNODES + col] = s[r2];
                if (bx != by)   // mirrored tile: contiguous float4 store
                    *(f32x4*)(out + (size_t)col * NNODES + row0) = s;
            }
        }
    }
}

extern "C" void kernel_launch(void* const* d_in, const int* in_sizes, int n_in,
                              void* d_out, int out_size, void* d_ws, size_t ws_size,
                              hipStream_t stream) {
    const bf16_t* x   = (const bf16_t*)d_in[0];
    const int*    ei  = (const int*)d_in[1];
    const bf16_t* W1  = (const bf16_t*)d_in[2];
    const bf16_t* as1 = (const bf16_t*)d_in[3];
    const bf16_t* ad1 = (const bf16_t*)d_in[4];
    const bf16_t* b1  = (const bf16_t*)d_in[5];
    const bf16_t* W2  = (const bf16_t*)d_in[6];
    const bf16_t* as2 = (const bf16_t*)d_in[7];
    const bf16_t* ad2 = (const bf16_t*)d_in[8];
    const bf16_t* b2  = (const bf16_t*)d_in[9];
    float* out = (float*)d_out;   // output 0 f32 [N][N], output 1 f32 [2][E]

    // Scratch lives inside d_out's adjacency region (576 MB f32), dead until
    // k_gemm_sig overwrites it. Only h2 (read during final GEMM) is in d_ws.
    char* obuf = (char*)d_out;
    size_t off = 0;
    auto carve = [&](size_t bytes) {
        char* p = obuf + off;
        off += (bytes + 255) & ~(size_t)255;
        return p;
    };
    float* h1pre  = (float*)carve((size_t)NNODES * FHID * 4);
    float* al1    = (float*)carve((size_t)NNODES * 4);
    float* ar1    = (float*)carve((size_t)NNODES * 4);
    float* h1     = (float*)carve((size_t)NNODES * FHID * 4);
    float* al2    = (float*)carve((size_t)NNODES * 4);
    float* ar2    = (float*)carve((size_t)NNODES * 4);
    int*   deg    = (int*)carve((size_t)NNODES * 4);
    int*   rowptr = (int*)carve((size_t)(NNODES + 1) * 4);
    int*   cursor = (int*)carve((size_t)NNODES * 4);
    int*   csrc   = (int*)carve((size_t)NETOT * 4);
    unsigned char* h2pre = (unsigned char*)carve((size_t)NNODES * KP);  // fp8
    bf16_t* h2 = (bf16_t*)d_ws;   // [MP][KP] bf16 = 34.65 MB
    (void)ws_size; (void)in_sizes; (void)n_in; (void)out_size;

    hipLaunchKernelGGL(k_init,    dim3(256), dim3(256), 0, stream, deg, h2);
    hipLaunchKernelGGL(k_count,   dim3((NEDGES + 255) / 256), dim3(256), 0, stream, ei, deg);
    hipLaunchKernelGGL(k_scan,    dim3(1), dim3(1024), 0, stream, deg, rowptr, cursor);
    hipLaunchKernelGGL(k_fill,    dim3((2 * NEDGES + 255) / 256), dim3(256), 0, stream,
                       ei, cursor, csrc, out);
    hipLaunchKernelGGL(k_linear1, dim3((NNODES + 255) / 256), dim3(256), 0, stream,
                       x, W1, as1, ad1, h1pre, al1, ar1);
    hipLaunchKernelGGL(k_agg1,    dim3(NNODES / 4), dim3(256), 0, stream,
                       h1pre, al1, ar1, rowptr, csrc, b1, h1);
    hipLaunchKernelGGL(k_linear2, dim3(NNODES / 4), dim3(256), 0, stream,
                       h1, W2, as2, ad2, h2pre, al2, ar2);
    hipLaunchKernelGGL(k_agg2,    dim3(NNODES), dim3(256), 0, stream,
                       h2pre, al2, ar2, rowptr, csrc, b2, h2);
    hipLaunchKernelGGL(k_gemm_sig, dim3(GTRI), dim3(512), 0, stream, h2, out);
}

// Round 2
// 1149.262 us; speedup vs baseline: 1.0129x; 1.0129x over previous
//
#include <hip/hip_runtime.h>
#include <hip/hip_bf16.h>

#define NNODES 12000
#define NEDGES 384000
#define NETOT  (NEDGES + NNODES)   /* 396000 incl self-loops */
#define FIN    4
#define FHID   50
#define FOUT   1433
#define KP     1440                /* FOUT padded to multiple of 32 */
#define MP     12032               /* NNODES padded to multiple of 256 */
#define GT     (MP / 256)          /* 47 tiles of 256 */
#define GTRI   (GT * (GT + 1) / 2) /* 1128 upper-triangle tiles */
#define NEG_SLOPE 0.2f

typedef __hip_bfloat16 bf16_t;
typedef __bf16 bf16x8 __attribute__((ext_vector_type(8)));
typedef float f32x4 __attribute__((ext_vector_type(4)));
typedef float f32x2 __attribute__((ext_vector_type(2)));

__device__ __forceinline__ float  b2f(bf16_t h) { return __bfloat162float(h); }
__device__ __forceinline__ bf16_t f2b(float f)  { return __float2bfloat16(f); }
__device__ __forceinline__ unsigned short f2bu(float f) { bf16_t h = f2b(f); return *(unsigned short*)&h; }

// ---------------- init: deg=1 (self loop), zero pad rows of h2 (bf16) ----------------
__global__ void k_init(int* __restrict__ deg, bf16_t* __restrict__ h2) {
    int i = blockIdx.x * blockDim.x + threadIdx.x;
    int stride = gridDim.x * blockDim.x;
    for (int v = i; v < NNODES; v += stride) deg[v] = 1;
    const size_t padN = (size_t)(MP - NNODES) * KP;
    for (size_t t = i; t < padN; t += stride) h2[(size_t)NNODES * KP + t] = f2b(0.f);
}

// ---------------- count real edges by dst ----------------
__global__ void k_count(const int* __restrict__ ei, int* __restrict__ deg) {
    int i = blockIdx.x * blockDim.x + threadIdx.x;
    if (i < NEDGES) atomicAdd(&deg[ei[NEDGES + i]], 1);
}

// ---------------- single-block shfl exclusive scan -> rowptr[N+1] + cursor[N] ----------------
// 12 elems/thread blocked; wave shfl-scan; 16-wave LDS combine; 2 barriers total.
__global__ __launch_bounds__(1024) void k_scan(const int* __restrict__ deg,
                                               int* __restrict__ rowptr,
                                               int* __restrict__ cursor) {
    __shared__ int wsum[16];
    const int tid = threadIdx.x, lane = tid & 63, wv = tid >> 6;
    const int base = tid * 12;
    int pref[12];
    int s = 0;
#pragma unroll
    for (int u = 0; u < 12; ++u) {
        int idx = base + u;
        int d = (idx < NNODES) ? deg[idx] : 0;
        pref[u] = s;
        s += d;
    }
    int sc = s;   // inclusive wave scan of per-thread sums
#pragma unroll
    for (int o = 1; o < 64; o <<= 1) {
        int t2 = __shfl_up(sc, o, 64);
        if (lane >= o) sc += t2;
    }
    if (lane == 63) wsum[wv] = sc;
    __syncthreads();
    if (wv == 0 && lane < 16) {
        int mine = wsum[lane];
        int scw = mine;
#pragma unroll
        for (int o = 1; o < 16; o <<= 1) {
            int t3 = __shfl_up(scw, o, 64);
            if (lane >= o) scw += t3;
        }
        wsum[lane] = scw - mine;   // exclusive wave prefix
    }
    __syncthreads();
    const int pre = wsum[wv] + (sc - s);   // exclusive prefix of this thread
#pragma unroll
    for (int u = 0; u < 12; ++u) {
        int idx = base + u;
        if (idx < NNODES) {
            int p = pre + pref[u];
            rowptr[idx] = p;
            cursor[idx] = p;
        }
    }
    if (tid == 1023) rowptr[NNODES] = pre + s;   // == NETOT
}

// ---------------- fill CSR src lists (incl self loops) + edge passthrough ----------------
__global__ void k_fill(const int* __restrict__ ei, int* __restrict__ cursor,
                       int* __restrict__ csrc, float* __restrict__ outbase) {
    int i = blockIdx.x * blockDim.x + threadIdx.x;
    if (i < NETOT) {
        int s, d;
        if (i < NEDGES) { s = ei[i]; d = ei[NEDGES + i]; }
        else            { s = d = i - NEDGES; }
        int pos = atomicAdd(&cursor[d], 1);
        csrc[pos] = s;
    }
    if (i < 2 * NEDGES)
        outbase[(size_t)NNODES * (size_t)NNODES + (size_t)i] = (float)ei[i];
}

// ---------------- layer1 linear: h1pre = x @ W1, al1/ar1 logit parts ----------------
__global__ __launch_bounds__(256) void k_linear1(
        const bf16_t* __restrict__ x, const bf16_t* __restrict__ W1,
        const bf16_t* __restrict__ as1, const bf16_t* __restrict__ ad1,
        float* __restrict__ h1pre, float* __restrict__ al, float* __restrict__ ar) {
    __shared__ float sW[FIN * FHID];
    __shared__ float sa[FHID], sdl[FHID];
    int tid = threadIdx.x;
    if (tid < FIN * FHID) sW[tid] = b2f(W1[tid]);
    if (tid < FHID) { sa[tid] = b2f(as1[tid]); sdl[tid] = b2f(ad1[tid]); }
    __syncthreads();
    int i = blockIdx.x * 256 + tid;
    if (i >= NNODES) return;
    float x0 = b2f(x[i * 4 + 0]), x1 = b2f(x[i * 4 + 1]);
    float x2 = b2f(x[i * 4 + 2]), x3 = b2f(x[i * 4 + 3]);
    float hal = 0.f, har = 0.f;
    for (int j = 0; j < FHID; ++j) {
        float h = x0 * sW[j] + x1 * sW[FHID + j] + x2 * sW[2 * FHID + j] + x3 * sW[3 * FHID + j];
        h1pre[(size_t)i * FHID + j] = h;
        hal += h * sa[j];
        har += h * sdl[j];
    }
    al[i] = hal; ar[i] = har;
}

// ---------------- layer1 softmax-aggregate: wave-per-node, no max pass, shfl broadcast ----------------
__global__ __launch_bounds__(256) void k_agg1(
        const float* __restrict__ h1pre, const float* __restrict__ al, const float* __restrict__ ar,
        const int* __restrict__ rowptr, const int* __restrict__ csrc,
        const bf16_t* __restrict__ b1, float* __restrict__ h1) {
    const int wv = threadIdx.x >> 6, lane = threadIdx.x & 63;
    const int v = blockIdx.x * 4 + wv;        // NNODES % 4 == 0
    const int s0 = rowptr[v], s1 = rowptr[v + 1];
    const float arv = ar[v];
    float acc = 0.f, ssum = 0.f;
    for (int base = s0; base < s1; base += 64) {
        int e = base + lane;
        float w = 0.f; int si = 0;
        if (e < s1) {
            si = csrc[e];
            float l = al[si] + arv;
            l = l > 0.f ? l : NEG_SLOPE * l;
            w = __expf(l);                     // softmax is shift-invariant; |l| small
        }
        ssum += w;
        int cnt = min(64, s1 - base);
#pragma unroll 4
        for (int j = 0; j < cnt; ++j) {
            float wj = __shfl(w, j, 64);
            int   sj = __shfl(si, j, 64);
            if (lane < FHID) acc += wj * h1pre[(size_t)sj * FHID + lane];
        }
    }
#pragma unroll
    for (int o = 32; o; o >>= 1) ssum += __shfl_xor(ssum, o, 64);
    if (lane < FHID) {
        float o2 = acc / ssum + b2f(b1[lane]);
        h1[(size_t)v * FHID + lane] = fmaxf(o2, 0.f);
    }
}

// ---------------- layer2 linear: 4 nodes/block, h2pre (fp8 e4m3) = h1 @ W2, al2/ar2 ----------------
__global__ __launch_bounds__(256) void k_linear2(
        const float* __restrict__ h1, const bf16_t* __restrict__ W2,
        const bf16_t* __restrict__ as2, const bf16_t* __restrict__ ad2,
        unsigned char* __restrict__ h2pre, float* __restrict__ al2, float* __restrict__ ar2) {
    int v0 = blockIdx.x * 4, tid = threadIdx.x;
    __shared__ float sh[4][FHID];
    if (tid < 4 * FHID) sh[tid / FHID][tid % FHID] = h1[(size_t)v0 * FHID + tid];
    __syncthreads();
    float pal[4] = {0.f, 0.f, 0.f, 0.f}, par[4] = {0.f, 0.f, 0.f, 0.f};
#pragma unroll
    for (int i = 0; i < 3; ++i) {
        int f0 = i * 512 + 2 * tid;          // even feature index
        if (f0 < KP) {
            float d0[4] = {0.f, 0.f, 0.f, 0.f}, d1[4] = {0.f, 0.f, 0.f, 0.f};
            bool ok0 = f0 < FOUT, ok1 = f0 + 1 < FOUT;
            if (ok0) {
                int f1 = ok1 ? f0 + 1 : f0;  // safe aliased read when f0+1 OOB
#pragma unroll 10
                for (int k = 0; k < FHID; ++k) {
                    float w0 = b2f(W2[k * FOUT + f0]);
                    float w1 = b2f(W2[k * FOUT + f1]);
#pragma unroll
                    for (int c = 0; c < 4; ++c) {
                        d0[c] += sh[c][k] * w0;
                        d1[c] += sh[c][k] * w1;
                    }
                }
                if (!ok1) { d1[0] = d1[1] = d1[2] = d1[3] = 0.f; }
                float sa0 = b2f(as2[f0]), sd0 = b2f(ad2[f0]);
                float sa1 = ok1 ? b2f(as2[f0 + 1]) : 0.f;
                float sd1 = ok1 ? b2f(ad2[f0 + 1]) : 0.f;
#pragma unroll
                for (int c = 0; c < 4; ++c) {
                    pal[c] += d0[c] * sa0 + d1[c] * sa1;
                    par[c] += d0[c] * sd0 + d1[c] * sd1;
                }
            }
#pragma unroll
            for (int c = 0; c < 4; ++c) {
                int pk = __builtin_amdgcn_cvt_pk_fp8_f32(d0[c], d1[c], 0, false);
                *(unsigned short*)(h2pre + (size_t)(v0 + c) * KP + f0) = (unsigned short)pk;
            }
        }
    }
#pragma unroll
    for (int off = 32; off; off >>= 1)
#pragma unroll
        for (int c = 0; c < 4; ++c) {
            pal[c] += __shfl_xor(pal[c], off, 64);
            par[c] += __shfl_xor(par[c], off, 64);
        }
    __shared__ float rA[4][4], rB[4][4];
    int wave = tid >> 6, lane = tid & 63;
    if (lane == 0)
#pragma unroll
        for (int c = 0; c < 4; ++c) { rA[wave][c] = pal[c]; rB[wave][c] = par[c]; }
    __syncthreads();
    if (tid < 4) {
        al2[v0 + tid] = rA[0][tid] + rA[1][tid] + rA[2][tid] + rA[3][tid];
        ar2[v0 + tid] = rB[0][tid] + rB[1][tid] + rB[2][tid] + rB[3][tid];
    }
}

// ---------------- layer2 softmax-aggregate: fp8 gather, no max pass, bf16 h2 out ----------------
__global__ __launch_bounds__(256) void k_agg2(
        const unsigned char* __restrict__ h2pre, const float* __restrict__ al, const float* __restrict__ ar,
        const int* __restrict__ rowptr, const int* __restrict__ csrc,
        const bf16_t* __restrict__ bias2, bf16_t* __restrict__ h2) {
    int v = blockIdx.x, tid = threadIdx.x;
    int s0 = rowptr[v], s1 = rowptr[v + 1];
    float arv = ar[v];
    int wave = tid >> 6, lane = tid & 63;

    float acc[8] = {0.f, 0.f, 0.f, 0.f, 0.f, 0.f, 0.f, 0.f};
    float ssum = 0.f;
    __shared__ float sw[256];
    __shared__ int ssrc[256];
    __shared__ float red[4];
    const bool act = tid < (KP / 8);          // 180 lanes cover the 1440-B row
    for (int base = s0; base < s1; base += 256) {
        int e = base + tid;
        float w = 0.f; int si = 0;
        if (e < s1) {
            si = csrc[e];
            float l = al[si] + arv;
            l = l > 0.f ? l : NEG_SLOPE * l;
            w = __expf(l);                    // shift-invariant; |l| small
        }
        ssum += w;
        sw[tid] = w; ssrc[tid] = si;
        __syncthreads();
        int cnt = min(256, s1 - base);
        if (act) {
#pragma unroll 8
            for (int j = 0; j < cnt; ++j) {
                float wj = sw[j];
                const uint2* hp = (const uint2*)(h2pre + (size_t)ssrc[j] * KP);
                uint2 p = hp[tid];
                f32x2 e0 = __builtin_amdgcn_cvt_pk_f32_fp8(p.x, false);
                f32x2 e1 = __builtin_amdgcn_cvt_pk_f32_fp8(p.x, true);
                f32x2 e2 = __builtin_amdgcn_cvt_pk_f32_fp8(p.y, false);
                f32x2 e3 = __builtin_amdgcn_cvt_pk_f32_fp8(p.y, true);
                acc[0] += wj * e0.x; acc[1] += wj * e0.y;
                acc[2] += wj * e1.x; acc[3] += wj * e1.y;
                acc[4] += wj * e2.x; acc[5] += wj * e2.y;
                acc[6] += wj * e3.x; acc[7] += wj * e3.y;
            }
        }
        __syncthreads();
    }
#pragma unroll
    for (int off = 32; off; off >>= 1) ssum += __shfl_xor(ssum, off, 64);
    if (lane == 0) red[wave] = ssum;
    __syncthreads();
    float inv = 1.f / (red[0] + red[1] + red[2] + red[3]);

    if (act) {
        int fb = 8 * tid;
        unsigned short o[8];
#pragma unroll
        for (int t = 0; t < 8; ++t) {
            int f = fb + t;
            o[t] = f2bu((f < FOUT) ? fmaxf(acc[t] * inv + b2f(bias2[f]), 0.f) : 0.f);
        }
        uint4 pk;
        pk.x = (unsigned)o[0] | ((unsigned)o[1] << 16);
        pk.y = (unsigned)o[2] | ((unsigned)o[3] << 16);
        pk.z = (unsigned)o[4] | ((unsigned)o[5] << 16);
        pk.w = (unsigned)o[6] | ((unsigned)o[7] << 16);
        *(uint4*)(h2 + (size_t)v * KP + fb) = pk;
    }
}

// ---------------- final: out = sigmoid(H @ H^T) ----------------
// 256x256 tile, 8 waves (2Mx4N), BK=64 double-buffered 128KiB LDS.
// LDS swizzle: byte ^= ((row&7)<<4)  (XOR byte bits 4-6 with row bits 0-2).
// The reader's column index occupies byte bits 4-6 (q*16 + ks*64), so this
// spreads the 16 rows of a ds_read_b128 across all 8 16B-slots of a 128B
// line (8 lanes/slot uniform = conflict-free). Applied as inverse-swizzled
// GLOBAL source + swizzled ds_read (both-sides rule); LDS dest stays linear.
// Counted s_waitcnt vmcnt(8) across raw s_barriers (never drain-0 in loop).
// K = 1440 = 22*64 + 32; 32-wide tail reads fragments straight from global.
__global__ __launch_bounds__(512, 2) void k_gemm_sig(const bf16_t* __restrict__ Hm,
                                                     float* __restrict__ out) {
    // decode linear tile id -> (by, bx) with bx >= by
    int t = blockIdx.x;
    int by = (int)((2 * GT + 1 - sqrtf((float)(2 * GT + 1) * (2 * GT + 1) - 8.0f * t)) * 0.5f);
    if (by < 0) by = 0;
    if (by > GT - 1) by = GT - 1;
    while (by + 1 < GT && (by + 1) * GT - ((by + 1) * by) / 2 <= t) ++by;
    while (by > 0 && by * GT - (by * (by - 1)) / 2 > t) --by;
    int bx = by + (t - (by * GT - (by * (by - 1)) / 2));

    __shared__ __align__(16) char ldsA[2 * 256 * 64 * 2];   // 64 KiB (2 slots)
    __shared__ __align__(16) char ldsB[2 * 256 * 64 * 2];   // 64 KiB

    const int tid  = threadIdx.x;
    const int wave = tid >> 6, lane = tid & 63;
    const int rowA0 = by * 256, rowB0 = bx * 256;

    // staging: LDS dest is linear (wave-uniform base + lane*16); the swizzle
    // f(b) = b ^ (((b>>7)&7)<<4) is an involution confined to bits 4-6, so we
    // read the GLOBAL source at the swizzled logical address.
    const int phys  = wave * 1024 + lane * 16;               // within one 8KB round
    const int physL = phys ^ (((phys >> 7) & 7) << 4);
    const int srow  = physL >> 7;                            // 0..63
    const int scol  = (physL & 127) >> 1;                    // element 0..63
    const bf16_t* gA0 = Hm + (size_t)(rowA0 + srow) * KP + scol;
    const bf16_t* gB0 = Hm + (size_t)(rowB0 + srow) * KP + scol;

#define STAGE_TILE(slot_, kt_) do {                                            \
        char* la_ = ldsA + (slot_) * 32768 + wave * 1024;                      \
        char* lb_ = ldsB + (slot_) * 32768 + wave * 1024;                      \
        _Pragma("unroll")                                                      \
        for (int c_ = 0; c_ < 4; ++c_)                                         \
            __builtin_amdgcn_global_load_lds(                                  \
                (const __attribute__((address_space(1))) void*)(gA0 + (size_t)(c_ * 64) * KP + (kt_) * 64), \
                (__attribute__((address_space(3))) void*)(la_ + c_ * 8192), 16, 0, 0); \
        _Pragma("unroll")                                                      \
        for (int c_ = 0; c_ < 4; ++c_)                                         \
            __builtin_amdgcn_global_load_lds(                                  \
                (const __attribute__((address_space(1))) void*)(gB0 + (size_t)(c_ * 64) * KP + (kt_) * 64), \
                (__attribute__((address_space(3))) void*)(lb_ + c_ * 8192), 16, 0, 0); \
    } while (0)

    const int wr = wave >> 2, wc = wave & 3;    // 2M x 4N wave grid
    const int r = lane & 15, q = lane >> 4;
    const int swz = (r & 7) << 4;               // row bits 0-2 -> byte bits 4-6
    const int aBase = wr * 16384 + r * 128;     // row byte base in A slot
    const int bBase = wc * 8192  + r * 128;     // row byte base in B slot

    f32x4 acc[8][4] = {};

    STAGE_TILE(0, 0);
    for (int kt = 0; kt < 22; ++kt) {
        if (kt < 21) {
            STAGE_TILE((kt + 1) & 1, kt + 1);
            __builtin_amdgcn_sched_barrier(0);
            asm volatile("s_waitcnt vmcnt(8)" ::: "memory");   // tile kt landed; kt+1 in flight
        } else {
            __builtin_amdgcn_sched_barrier(0);
            asm volatile("s_waitcnt vmcnt(0)" ::: "memory");   // last tile: drain
        }
        __builtin_amdgcn_s_barrier();
        __builtin_amdgcn_sched_barrier(0);
        const char* Ab = ldsA + (kt & 1) * 32768;
        const char* Bb = ldsB + (kt & 1) * 32768;
#pragma unroll
        for (int ks = 0; ks < 2; ++ks) {
            const int cb = (ks * 64 + q * 16) ^ swz;
            bf16x8 af[8], bfr[4];
#pragma unroll
            for (int mi = 0; mi < 8; ++mi)
                af[mi] = *(const bf16x8*)(Ab + aBase + mi * 2048 + cb);
#pragma unroll
            for (int ni = 0; ni < 4; ++ni)
                bfr[ni] = *(const bf16x8*)(Bb + bBase + ni * 2048 + cb);
#pragma unroll
            for (int mi = 0; mi < 8; ++mi)
#pragma unroll
                for (int ni = 0; ni < 4; ++ni)
                    acc[mi][ni] = __builtin_amdgcn_mfma_f32_16x16x32_bf16(af[mi], bfr[ni], acc[mi][ni], 0, 0, 0);
        }
        __builtin_amdgcn_sched_barrier(0);
        __builtin_amdgcn_s_barrier();
        __builtin_amdgcn_sched_barrier(0);
    }
#undef STAGE_TILE

    // K tail: columns 1408..1439, fragments straight from global
    {
        bf16x8 at[8], bt[4];
#pragma unroll
        for (int mi = 0; mi < 8; ++mi)
            at[mi] = *(const bf16x8*)(Hm + (size_t)(rowA0 + wr * 128 + mi * 16 + r) * KP + 1408 + q * 8);
#pragma unroll
        for (int ni = 0; ni < 4; ++ni)
            bt[ni] = *(const bf16x8*)(Hm + (size_t)(rowB0 + wc * 64 + ni * 16 + r) * KP + 1408 + q * 8);
#pragma unroll
        for (int mi = 0; mi < 8; ++mi)
#pragma unroll
            for (int ni = 0; ni < 4; ++ni)
                acc[mi][ni] = __builtin_amdgcn_mfma_f32_16x16x32_bf16(at[mi], bt[ni], acc[mi][ni], 0, 0, 0);
    }

    // epilogue. C/D layout: col=lane&15, row=(lane>>4)*4+reg. NNODES%4==0.
#pragma unroll
    for (int mi = 0; mi < 8; ++mi) {
        const int row0 = rowA0 + wr * 128 + mi * 16 + q * 4;
#pragma unroll
        for (int ni = 0; ni < 4; ++ni) {
            const int col = rowB0 + wc * 64 + ni * 16 + r;
            if (col < NNODES && row0 < NNODES) {
                f32x4 s;
#pragma unroll
                for (int r2 = 0; r2 < 4; ++r2)
                    s[r2] = 1.f / (1.f + __expf(-acc[mi][ni][r2]));
#pragma unroll
                for (int r2 = 0; r2 < 4; ++r2)
                    out[(size_t)(row0 + r2) * NNODES + col] = s[r2];
                if (bx != by)   // mirrored tile: contiguous float4 store
                    *(f32x4*)(out + (size_t)col * NNODES + row0) = s;
            }
        }
    }
}

extern "C" void kernel_launch(void* const* d_in, const int* in_sizes, int n_in,
                              void* d_out, int out_size, void* d_ws, size_t ws_size,
                              hipStream_t stream) {
    const bf16_t* x   = (const bf16_t*)d_in[0];
    const int*    ei  = (const int*)d_in[1];
    const bf16_t* W1  = (const bf16_t*)d_in[2];
    const bf16_t* as1 = (const bf16_t*)d_in[3];
    const bf16_t* ad1 = (const bf16_t*)d_in[4];
    const bf16_t* b1  = (const bf16_t*)d_in[5];
    const bf16_t* W2  = (const bf16_t*)d_in[6];
    const bf16_t* as2 = (const bf16_t*)d_in[7];
    const bf16_t* ad2 = (const bf16_t*)d_in[8];
    const bf16_t* b2  = (const bf16_t*)d_in[9];
    float* out = (float*)d_out;   // output 0 f32 [N][N], output 1 f32 [2][E]

    // Scratch lives inside d_out's adjacency region (576 MB f32), dead until
    // k_gemm_sig overwrites it. Only h2 (read during final GEMM) is in d_ws.
    char* obuf = (char*)d_out;
    size_t off = 0;
    auto carve = [&](size_t bytes) {
        char* p = obuf + off;
        off += (bytes + 255) & ~(size_t)255;
        return p;
    };
    float* h1pre  = (float*)carve((size_t)NNODES * FHID * 4);
    float* al1    = (float*)carve((size_t)NNODES * 4);
    float* ar1    = (float*)carve((size_t)NNODES * 4);
    float* h1     = (float*)carve((size_t)NNODES * FHID * 4);
    float* al2    = (float*)carve((size_t)NNODES * 4);
    float* ar2    = (float*)carve((size_t)NNODES * 4);
    int*   deg    = (int*)carve((size_t)NNODES * 4);
    int*   rowptr = (int*)carve((size_t)(NNODES + 1) * 4);
    int*   cursor = (int*)carve((size_t)NNODES * 4);
    int*   csrc   = (int*)carve((size_t)NETOT * 4);
    unsigned char* h2pre = (unsigned char*)carve((size_t)NNODES * KP);  // fp8
    bf16_t* h2 = (bf16_t*)d_ws;   // [MP][KP] bf16 = 34.65 MB
    (void)ws_size; (void)in_sizes; (void)n_in; (void)out_size;

    hipLaunchKernelGGL(k_init,    dim3(256), dim3(256), 0, stream, deg, h2);
    hipLaunchKernelGGL(k_count,   dim3((NEDGES + 255) / 256), dim3(256), 0, stream, ei, deg);
    hipLaunchKernelGGL(k_scan,    dim3(1), dim3(1024), 0, stream, deg, rowptr, cursor);
    hipLaunchKernelGGL(k_fill,    dim3((2 * NEDGES + 255) / 256), dim3(256), 0, stream,
                       ei, cursor, csrc, out);
    hipLaunchKernelGGL(k_linear1, dim3((NNODES + 255) / 256), dim3(256), 0, stream,
                       x, W1, as1, ad1, h1pre, al1, ar1);
    hipLaunchKernelGGL(k_agg1,    dim3(NNODES / 4), dim3(256), 0, stream,
                       h1pre, al1, ar1, rowptr, csrc, b1, h1);
    hipLaunchKernelGGL(k_linear2, dim3(NNODES / 4), dim3(256), 0, stream,
                       h1, W2, as2, ad2, h2pre, al2, ar2);
    hipLaunchKernelGGL(k_agg2,    dim3(NNODES), dim3(256), 0, stream,
                       h2pre, al2, ar2, rowptr, csrc, b2, h2);
    hipLaunchKernelGGL(k_gemm_sig, dim3(GTRI), dim3(512), 0, stream, h2, out);
}

// Round 3
// 1134.131 us; speedup vs baseline: 1.0265x; 1.0133x over previous
//
#include <hip/hip_runtime.h>
#include <hip/hip_bf16.h>

#define NNODES 12000
#define NEDGES 384000
#define NETOT  (NEDGES + NNODES)   /* 396000 incl self-loops */
#define FIN    4
#define FHID   50
#define FOUT   1433
#define KP     1440                /* FOUT padded to multiple of 32 */
#define MP     12032               /* NNODES padded to multiple of 256 */
#define GT     (MP / 256)          /* 47 tiles of 256 */
#define GTRI   (GT * (GT + 1) / 2) /* 1128 upper-triangle tiles = 8*141 */
#define NEG_SLOPE 0.2f

typedef __hip_bfloat16 bf16_t;
typedef __bf16 bf16x8 __attribute__((ext_vector_type(8)));
typedef float f32x4 __attribute__((ext_vector_type(4)));
typedef float f32x2 __attribute__((ext_vector_type(2)));

__device__ __forceinline__ float  b2f(bf16_t h) { return __bfloat162float(h); }
__device__ __forceinline__ bf16_t f2b(float f)  { return __float2bfloat16(f); }
__device__ __forceinline__ unsigned short f2bu(float f) { bf16_t h = f2b(f); return *(unsigned short*)&h; }

// ---------------- init: deg=1 (self loop), zero pad rows of h2 (bf16) ----------------
__global__ void k_init(int* __restrict__ deg, bf16_t* __restrict__ h2) {
    int i = blockIdx.x * blockDim.x + threadIdx.x;
    int stride = gridDim.x * blockDim.x;
    for (int v = i; v < NNODES; v += stride) deg[v] = 1;
    const size_t padN = (size_t)(MP - NNODES) * KP;
    for (size_t t = i; t < padN; t += stride) h2[(size_t)NNODES * KP + t] = f2b(0.f);
}

// ---------------- count real edges by dst ----------------
__global__ void k_count(const int* __restrict__ ei, int* __restrict__ deg) {
    int i = blockIdx.x * blockDim.x + threadIdx.x;
    if (i < NEDGES) atomicAdd(&deg[ei[NEDGES + i]], 1);
}

// ---------------- single-block shfl exclusive scan -> rowptr[N+1] + cursor[N] ----------------
__global__ __launch_bounds__(1024) void k_scan(const int* __restrict__ deg,
                                               int* __restrict__ rowptr,
                                               int* __restrict__ cursor) {
    __shared__ int wsum[16];
    const int tid = threadIdx.x, lane = tid & 63, wv = tid >> 6;
    const int base = tid * 12;
    int pref[12];
    int s = 0;
#pragma unroll
    for (int u = 0; u < 12; ++u) {
        int idx = base + u;
        int d = (idx < NNODES) ? deg[idx] : 0;
        pref[u] = s;
        s += d;
    }
    int sc = s;   // inclusive wave scan of per-thread sums
#pragma unroll
    for (int o = 1; o < 64; o <<= 1) {
        int t2 = __shfl_up(sc, o, 64);
        if (lane >= o) sc += t2;
    }
    if (lane == 63) wsum[wv] = sc;
    __syncthreads();
    if (wv == 0 && lane < 16) {
        int mine = wsum[lane];
        int scw = mine;
#pragma unroll
        for (int o = 1; o < 16; o <<= 1) {
            int t3 = __shfl_up(scw, o, 64);
            if (lane >= o) scw += t3;
        }
        wsum[lane] = scw - mine;   // exclusive wave prefix
    }
    __syncthreads();
    const int pre = wsum[wv] + (sc - s);   // exclusive prefix of this thread
#pragma unroll
    for (int u = 0; u < 12; ++u) {
        int idx = base + u;
        if (idx < NNODES) {
            int p = pre + pref[u];
            rowptr[idx] = p;
            cursor[idx] = p;
        }
    }
    if (tid == 1023) rowptr[NNODES] = pre + s;   // == NETOT
}

// ---------------- fill CSR src lists (incl self loops) + edge passthrough ----------------
__global__ void k_fill(const int* __restrict__ ei, int* __restrict__ cursor,
                       int* __restrict__ csrc, float* __restrict__ outbase) {
    int i = blockIdx.x * blockDim.x + threadIdx.x;
    if (i < NETOT) {
        int s, d;
        if (i < NEDGES) { s = ei[i]; d = ei[NEDGES + i]; }
        else            { s = d = i - NEDGES; }
        int pos = atomicAdd(&cursor[d], 1);
        csrc[pos] = s;
    }
    if (i < 2 * NEDGES)
        outbase[(size_t)NNODES * (size_t)NNODES + (size_t)i] = (float)ei[i];
}

// ---------------- layer1 linear: h1pre = x @ W1, al1/ar1 logit parts ----------------
__global__ __launch_bounds__(256) void k_linear1(
        const bf16_t* __restrict__ x, const bf16_t* __restrict__ W1,
        const bf16_t* __restrict__ as1, const bf16_t* __restrict__ ad1,
        float* __restrict__ h1pre, float* __restrict__ al, float* __restrict__ ar) {
    __shared__ float sW[FIN * FHID];
    __shared__ float sa[FHID], sdl[FHID];
    int tid = threadIdx.x;
    if (tid < FIN * FHID) sW[tid] = b2f(W1[tid]);
    if (tid < FHID) { sa[tid] = b2f(as1[tid]); sdl[tid] = b2f(ad1[tid]); }
    __syncthreads();
    int i = blockIdx.x * 256 + tid;
    if (i >= NNODES) return;
    float x0 = b2f(x[i * 4 + 0]), x1 = b2f(x[i * 4 + 1]);
    float x2 = b2f(x[i * 4 + 2]), x3 = b2f(x[i * 4 + 3]);
    float hal = 0.f, har = 0.f;
    for (int j = 0; j < FHID; ++j) {
        float h = x0 * sW[j] + x1 * sW[FHID + j] + x2 * sW[2 * FHID + j] + x3 * sW[3 * FHID + j];
        h1pre[(size_t)i * FHID + j] = h;
        hal += h * sa[j];
        har += h * sdl[j];
    }
    al[i] = hal; ar[i] = har;
}

// ---------------- layer1 softmax-aggregate ----------------
__global__ __launch_bounds__(256) void k_agg1(
        const float* __restrict__ h1pre, const float* __restrict__ al, const float* __restrict__ ar,
        const int* __restrict__ rowptr, const int* __restrict__ csrc,
        const bf16_t* __restrict__ b1, float* __restrict__ h1) {
    const int wv = threadIdx.x >> 6, lane = threadIdx.x & 63;
    const int v = blockIdx.x * 4 + wv;        // NNODES % 4 == 0
    const int s0 = rowptr[v], s1 = rowptr[v + 1];
    const float arv = ar[v];
    float acc = 0.f, ssum = 0.f;
    for (int base = s0; base < s1; base += 64) {
        int e = base + lane;
        float w = 0.f; int si = 0;
        if (e < s1) {
            si = csrc[e];
            float l = al[si] + arv;
            l = l > 0.f ? l : NEG_SLOPE * l;
            w = __expf(l);                     // softmax is shift-invariant; |l| small
        }
        ssum += w;
        int cnt = min(64, s1 - base);
#pragma unroll 4
        for (int j = 0; j < cnt; ++j) {
            float wj = __shfl(w, j, 64);
            int   sj = __shfl(si, j, 64);
            if (lane < FHID) acc += wj * h1pre[(size_t)sj * FHID + lane];
        }
    }
#pragma unroll
    for (int o = 32; o; o >>= 1) ssum += __shfl_xor(ssum, o, 64);
    if (lane < FHID) {
        float o2 = acc / ssum + b2f(b1[lane]);
        h1[(size_t)v * FHID + lane] = fmaxf(o2, 0.f);
    }
}

// ---------------- layer2 linear: 4 nodes/block, h2pre (fp8 e4m3) = h1 @ W2, al2/ar2 ----------------
__global__ __launch_bounds__(256) void k_linear2(
        const float* __restrict__ h1, const bf16_t* __restrict__ W2,
        const bf16_t* __restrict__ as2, const bf16_t* __restrict__ ad2,
        unsigned char* __restrict__ h2pre, float* __restrict__ al2, float* __restrict__ ar2) {
    int v0 = blockIdx.x * 4, tid = threadIdx.x;
    __shared__ float sh[4][FHID];
    if (tid < 4 * FHID) sh[tid / FHID][tid % FHID] = h1[(size_t)v0 * FHID + tid];
    __syncthreads();
    float pal[4] = {0.f, 0.f, 0.f, 0.f}, par[4] = {0.f, 0.f, 0.f, 0.f};
#pragma unroll
    for (int i = 0; i < 3; ++i) {
        int f0 = i * 512 + 2 * tid;          // even feature index
        if (f0 < KP) {
            float d0[4] = {0.f, 0.f, 0.f, 0.f}, d1[4] = {0.f, 0.f, 0.f, 0.f};
            bool ok0 = f0 < FOUT, ok1 = f0 + 1 < FOUT;
            if (ok0) {
                int f1 = ok1 ? f0 + 1 : f0;  // safe aliased read when f0+1 OOB
#pragma unroll 10
                for (int k = 0; k < FHID; ++k) {
                    float w0 = b2f(W2[k * FOUT + f0]);
                    float w1 = b2f(W2[k * FOUT + f1]);
#pragma unroll
                    for (int c = 0; c < 4; ++c) {
                        d0[c] += sh[c][k] * w0;
                        d1[c] += sh[c][k] * w1;
                    }
                }
                if (!ok1) { d1[0] = d1[1] = d1[2] = d1[3] = 0.f; }
                float sa0 = b2f(as2[f0]), sd0 = b2f(ad2[f0]);
                float sa1 = ok1 ? b2f(as2[f0 + 1]) : 0.f;
                float sd1 = ok1 ? b2f(ad2[f0 + 1]) : 0.f;
#pragma unroll
                for (int c = 0; c < 4; ++c) {
                    pal[c] += d0[c] * sa0 + d1[c] * sa1;
                    par[c] += d0[c] * sd0 + d1[c] * sd1;
                }
            }
#pragma unroll
            for (int c = 0; c < 4; ++c) {
                int pk = __builtin_amdgcn_cvt_pk_fp8_f32(d0[c], d1[c], 0, false);
                *(unsigned short*)(h2pre + (size_t)(v0 + c) * KP + f0) = (unsigned short)pk;
            }
        }
    }
#pragma unroll
    for (int off = 32; off; off >>= 1)
#pragma unroll
        for (int c = 0; c < 4; ++c) {
            pal[c] += __shfl_xor(pal[c], off, 64);
            par[c] += __shfl_xor(par[c], off, 64);
        }
    __shared__ float rA[4][4], rB[4][4];
    int wave = tid >> 6, lane = tid & 63;
    if (lane == 0)
#pragma unroll
        for (int c = 0; c < 4; ++c) { rA[wave][c] = pal[c]; rB[wave][c] = par[c]; }
    __syncthreads();
    if (tid < 4) {
        al2[v0 + tid] = rA[0][tid] + rA[1][tid] + rA[2][tid] + rA[3][tid];
        ar2[v0 + tid] = rB[0][tid] + rB[1][tid] + rB[2][tid] + rB[3][tid];
    }
}

// ---------------- layer2 softmax-aggregate: fp8 gather, no max pass, bf16 h2 out ----------------
__global__ __launch_bounds__(256) void k_agg2(
        const unsigned char* __restrict__ h2pre, const float* __restrict__ al, const float* __restrict__ ar,
        const int* __restrict__ rowptr, const int* __restrict__ csrc,
        const bf16_t* __restrict__ bias2, bf16_t* __restrict__ h2) {
    int v = blockIdx.x, tid = threadIdx.x;
    int s0 = rowptr[v], s1 = rowptr[v + 1];
    float arv = ar[v];
    int wave = tid >> 6, lane = tid & 63;

    float acc[8] = {0.f, 0.f, 0.f, 0.f, 0.f, 0.f, 0.f, 0.f};
    float ssum = 0.f;
    __shared__ float sw[256];
    __shared__ int ssrc[256];
    __shared__ float red[4];
    const bool act = tid < (KP / 8);          // 180 lanes cover the 1440-B row
    for (int base = s0; base < s1; base += 256) {
        int e = base + tid;
        float w = 0.f; int si = 0;
        if (e < s1) {
            si = csrc[e];
            float l = al[si] + arv;
            l = l > 0.f ? l : NEG_SLOPE * l;
            w = __expf(l);                    // shift-invariant; |l| small
        }
        ssum += w;
        sw[tid] = w; ssrc[tid] = si;
        __syncthreads();
        int cnt = min(256, s1 - base);
        if (act) {
#pragma unroll 8
            for (int j = 0; j < cnt; ++j) {
                float wj = sw[j];
                const uint2* hp = (const uint2*)(h2pre + (size_t)ssrc[j] * KP);
                uint2 p = hp[tid];
                f32x2 e0 = __builtin_amdgcn_cvt_pk_f32_fp8(p.x, false);
                f32x2 e1 = __builtin_amdgcn_cvt_pk_f32_fp8(p.x, true);
                f32x2 e2 = __builtin_amdgcn_cvt_pk_f32_fp8(p.y, false);
                f32x2 e3 = __builtin_amdgcn_cvt_pk_f32_fp8(p.y, true);
                acc[0] += wj * e0.x; acc[1] += wj * e0.y;
                acc[2] += wj * e1.x; acc[3] += wj * e1.y;
                acc[4] += wj * e2.x; acc[5] += wj * e2.y;
                acc[6] += wj * e3.x; acc[7] += wj * e3.y;
            }
        }
        __syncthreads();
    }
#pragma unroll
    for (int off = 32; off; off >>= 1) ssum += __shfl_xor(ssum, off, 64);
    if (lane == 0) red[wave] = ssum;
    __syncthreads();
    float inv = 1.f / (red[0] + red[1] + red[2] + red[3]);

    if (act) {
        int fb = 8 * tid;
        unsigned short o[8];
#pragma unroll
        for (int t = 0; t < 8; ++t) {
            int f = fb + t;
            o[t] = f2bu((f < FOUT) ? fmaxf(acc[t] * inv + b2f(bias2[f]), 0.f) : 0.f);
        }
        uint4 pk;
        pk.x = (unsigned)o[0] | ((unsigned)o[1] << 16);
        pk.y = (unsigned)o[2] | ((unsigned)o[3] << 16);
        pk.z = (unsigned)o[4] | ((unsigned)o[5] << 16);
        pk.w = (unsigned)o[6] | ((unsigned)o[7] << 16);
        *(uint4*)(h2 + (size_t)v * KP + fb) = pk;
    }
}

// ---------------- final: out = sigmoid(H @ H^T), 8-phase 256x256 MFMA GEMM ----------------
// 8 waves (2Mx4N), BK=64. LDS = 2 slots x (A 32KB + B 32KB) = 128 KiB, staged as
// K-HALVES: 256 rows x 32 cols, row stride 64 B. With 64-B rows, the fragment read
// addr = row*64 + q*16 puts bit6=row&1 -> 8 lanes per 16B slot, uniform =
// conflict-free with LINEAR LDS (no swizzle, no source permutation needed).
// Per K-tile: 4 phases {ds_read 4-8 b128 | stage 1 K-half (2 gload_lds) ->
// s_barrier -> lgkmcnt(0) -> setprio(1) 16 MFMA setprio(0) -> s_barrier}.
// Counted waits: vmcnt(4) at local phases 1 & 3 is EXACT (tile t+1's kh staged
// at phase p is first read 2 phases later; wait leaves exactly 2 K-halves in
// flight). Never drains to 0 except the last tile (epilogue drain).
// K = 1440 = 22*64 + 32; 32-wide tail reads fragments straight from global.
// Grid = 1128 = 8*141: bijective XCD swizzle on the triangular tile id.
__global__ __launch_bounds__(512, 2) void k_gemm_sig(const bf16_t* __restrict__ Hm,
                                                     float* __restrict__ out) {
    // XCD-aware swizzle (1128 % 8 == 0 -> simple form is bijective)
    int t0 = (blockIdx.x & 7) * (GTRI / 8) + (blockIdx.x >> 3);
    // decode linear tile id -> (by, bx) with bx >= by
    int by = (int)((2 * GT + 1 - sqrtf((float)(2 * GT + 1) * (2 * GT + 1) - 8.0f * t0)) * 0.5f);
    if (by < 0) by = 0;
    if (by > GT - 1) by = GT - 1;
    while (by + 1 < GT && (by + 1) * GT - ((by + 1) * by) / 2 <= t0) ++by;
    while (by > 0 && by * GT - (by * (by - 1)) / 2 > t0) --by;
    int bx = by + (t0 - (by * GT - (by * (by - 1)) / 2));

    __shared__ __align__(16) char lds[131072];

    const int tid  = threadIdx.x;
    const int wave = tid >> 6, lane = tid & 63;
    const int rowA0 = by * 256, rowB0 = bx * 256;
    const int wr = wave >> 2, wc = wave & 3;    // 2M x 4N wave grid
    const int r = lane & 15, q4 = lane >> 4;

    // staging source: linear byte index within a 16 KB K-half -> (row, col)
    const int lin  = wave * 1024 + lane * 16;        // 0..8191 (c adds 8192)
    const int grow = lin >> 6;                       // 0..127
    const int gcol = (lin & 63) >> 1;                // element col 0..31
    const bf16_t* gAs = Hm + (size_t)(rowA0 + grow) * KP + gcol;
    const bf16_t* gBs = Hm + (size_t)(rowB0 + grow) * KP + gcol;

    // fragment read offsets within a K-half (row stride 64 B)
    const int aOff = (wr * 128 + r) * 64 + q4 * 16;
    const int bOff = (wc * 64  + r) * 64 + q4 * 16;

    f32x4 acc[8][4] = {};
    bf16x8 af[4], bfr[4];

// stage one K-half (kh: 0=A-ks0, 1=B-ks0, 2=A-ks1, 3=B-ks1) of K-tile kt_ into slot ns_
#define STAGE_KH(ns_, kt_, kh_) do {                                             \
        const bf16_t* gs_ = ((kh_) & 1) ? gBs : gAs;                             \
        char* ld_ = lds + (ns_) * 65536 + ((kh_) & 1) * 32768                    \
                        + ((kh_) >> 1) * 16384 + wave * 1024;                    \
        const int kc_ = (kt_) * 64 + ((kh_) >> 1) * 32;                          \
        __builtin_amdgcn_global_load_lds(                                        \
            (const __attribute__((address_space(1))) void*)(gs_ + kc_),          \
            (__attribute__((address_space(3))) void*)ld_, 16, 0, 0);             \
        __builtin_amdgcn_global_load_lds(                                        \
            (const __attribute__((address_space(1))) void*)(gs_ + kc_ + (size_t)128 * KP), \
            (__attribute__((address_space(3))) void*)(ld_ + 8192), 16, 0, 0);    \
    } while (0)

#define LOAD_BFR(Bb_, ks_) { _Pragma("unroll") for (int n_ = 0; n_ < 4; ++n_)    \
        bfr[n_] = *(const bf16x8*)((Bb_) + (ks_) * 16384 + bOff + n_ * 1024); }
#define LOAD_AF(Ab_, ks_, mh_) { _Pragma("unroll") for (int m_ = 0; m_ < 4; ++m_) \
        af[m_] = *(const bf16x8*)((Ab_) + (ks_) * 16384 + aOff + (mh_) * 4096 + m_ * 1024); }

#define MFMA16(mh_) {                                                            \
        __builtin_amdgcn_s_setprio(1);                                           \
        _Pragma("unroll") for (int m_ = 0; m_ < 4; ++m_)                         \
        _Pragma("unroll") for (int n_ = 0; n_ < 4; ++n_)                         \
            acc[(mh_) * 4 + m_][n_] = __builtin_amdgcn_mfma_f32_16x16x32_bf16(   \
                af[m_], bfr[n_], acc[(mh_) * 4 + m_][n_], 0, 0, 0);              \
        __builtin_amdgcn_s_setprio(0); }

#define SYNC_PRE()  { __builtin_amdgcn_s_barrier();                              \
        asm volatile("s_waitcnt lgkmcnt(0)" ::: "memory");                       \
        __builtin_amdgcn_sched_barrier(0); }
#define SYNC_POST() { __builtin_amdgcn_sched_barrier(0); __builtin_amdgcn_s_barrier(); }

    // prologue: stage tile 0 fully; leave its last 2 K-halves in flight
    STAGE_KH(0, 0, 0); STAGE_KH(0, 0, 1); STAGE_KH(0, 0, 2); STAGE_KH(0, 0, 3);
    asm volatile("s_waitcnt vmcnt(4)" ::: "memory");
    __builtin_amdgcn_s_barrier();

#pragma unroll 1
    for (int t = 0; t < 22; ++t) {
        const int sl = t & 1, ns = sl ^ 1;
        const char* Ab = lds + sl * 65536;
        const char* Bb = lds + sl * 65536 + 32768;
        const bool st = (t < 21);
        // phase 0: ks=0, mi 0-3
        LOAD_BFR(Bb, 0); LOAD_AF(Ab, 0, 0);
        if (st) STAGE_KH(ns, t + 1, 0);
        SYNC_PRE(); MFMA16(0); SYNC_POST();
        // phase 1: ks=0, mi 4-7   [vmcnt guards next phase's A/B ks=1 reads]
        LOAD_AF(Ab, 0, 1);
        if (st) { STAGE_KH(ns, t + 1, 1); asm volatile("s_waitcnt vmcnt(4)" ::: "memory"); }
        else    { asm volatile("s_waitcnt vmcnt(0)" ::: "memory"); }
        SYNC_PRE(); MFMA16(1); SYNC_POST();
        // phase 2: ks=1, mi 0-3
        LOAD_BFR(Bb, 1); LOAD_AF(Ab, 1, 0);
        if (st) STAGE_KH(ns, t + 1, 2);
        SYNC_PRE(); MFMA16(0); SYNC_POST();
        // phase 3: ks=1, mi 4-7   [vmcnt guards next tile's phase-0 reads]
        LOAD_AF(Ab, 1, 1);
        if (st) { STAGE_KH(ns, t + 1, 3); asm volatile("s_waitcnt vmcnt(4)" ::: "memory"); }
        SYNC_PRE(); MFMA16(1); SYNC_POST();
    }
#undef STAGE_KH

    // K tail: columns 1408..1439, fragments straight from global (H is L2/L3-hot)
    {
        bf16x8 at[8], bt[4];
#pragma unroll
        for (int mi = 0; mi < 8; ++mi)
            at[mi] = *(const bf16x8*)(Hm + (size_t)(rowA0 + wr * 128 + mi * 16 + r) * KP + 1408 + q4 * 8);
#pragma unroll
        for (int ni = 0; ni < 4; ++ni)
            bt[ni] = *(const bf16x8*)(Hm + (size_t)(rowB0 + wc * 64 + ni * 16 + r) * KP + 1408 + q4 * 8);
#pragma unroll
        for (int mi = 0; mi < 8; ++mi)
#pragma unroll
            for (int ni = 0; ni < 4; ++ni)
                acc[mi][ni] = __builtin_amdgcn_mfma_f32_16x16x32_bf16(at[mi], bt[ni], acc[mi][ni], 0, 0, 0);
    }

    // epilogue. C/D layout: col=lane&15, row=(lane>>4)*4+reg. NNODES%4==0.
#pragma unroll
    for (int mi = 0; mi < 8; ++mi) {
        const int row0 = rowA0 + wr * 128 + mi * 16 + q4 * 4;
#pragma unroll
        for (int ni = 0; ni < 4; ++ni) {
            const int col = rowB0 + wc * 64 + ni * 16 + r;
            if (col < NNODES && row0 < NNODES) {
                f32x4 s;
#pragma unroll
                for (int r2 = 0; r2 < 4; ++r2)
                    s[r2] = 1.f / (1.f + __expf(-acc[mi][ni][r2]));
#pragma unroll
                for (int r2 = 0; r2 < 4; ++r2)
                    out[(size_t)(row0 + r2) * NNODES + col] = s[r2];
                if (bx != by)   // mirrored tile: contiguous float4 store
                    *(f32x4*)(out + (size_t)col * NNODES + row0) = s;
            }
        }
    }
}

extern "C" void kernel_launch(void* const* d_in, const int* in_sizes, int n_in,
                              void* d_out, int out_size, void* d_ws, size_t ws_size,
                              hipStream_t stream) {
    const bf16_t* x   = (const bf16_t*)d_in[0];
    const int*    ei  = (const int*)d_in[1];
    const bf16_t* W1  = (const bf16_t*)d_in[2];
    const bf16_t* as1 = (const bf16_t*)d_in[3];
    const bf16_t* ad1 = (const bf16_t*)d_in[4];
    const bf16_t* b1  = (const bf16_t*)d_in[5];
    const bf16_t* W2  = (const bf16_t*)d_in[6];
    const bf16_t* as2 = (const bf16_t*)d_in[7];
    const bf16_t* ad2 = (const bf16_t*)d_in[8];
    const bf16_t* b2  = (const bf16_t*)d_in[9];
    float* out = (float*)d_out;   // output 0 f32 [N][N], output 1 f32 [2][E]

    // Scratch lives inside d_out's adjacency region (576 MB f32), dead until
    // k_gemm_sig overwrites it. Only h2 (read during final GEMM) is in d_ws.
    char* obuf = (char*)d_out;
    size_t off = 0;
    auto carve = [&](size_t bytes) {
        char* p = obuf + off;
        off += (bytes + 255) & ~(size_t)255;
        return p;
    };
    float* h1pre  = (float*)carve((size_t)NNODES * FHID * 4);
    float* al1    = (float*)carve((size_t)NNODES * 4);
    float* ar1    = (float*)carve((size_t)NNODES * 4);
    float* h1     = (float*)carve((size_t)NNODES * FHID * 4);
    float* al2    = (float*)carve((size_t)NNODES * 4);
    float* ar2    = (float*)carve((size_t)NNODES * 4);
    int*   deg    = (int*)carve((size_t)NNODES * 4);
    int*   rowptr = (int*)carve((size_t)(NNODES + 1) * 4);
    int*   cursor = (int*)carve((size_t)NNODES * 4);
    int*   csrc   = (int*)carve((size_t)NETOT * 4);
    unsigned char* h2pre = (unsigned char*)carve((size_t)NNODES * KP);  // fp8
    bf16_t* h2 = (bf16_t*)d_ws;   // [MP][KP] bf16 = 34.65 MB
    (void)ws_size; (void)in_sizes; (void)n_in; (void)out_size;

    hipLaunchKernelGGL(k_init,    dim3(256), dim3(256), 0, stream, deg, h2);
    hipLaunchKernelGGL(k_count,   dim3((NEDGES + 255) / 256), dim3(256), 0, stream, ei, deg);
    hipLaunchKernelGGL(k_scan,    dim3(1), dim3(1024), 0, stream, deg, rowptr, cursor);
    hipLaunchKernelGGL(k_fill,    dim3((2 * NEDGES + 255) / 256), dim3(256), 0, stream,
                       ei, cursor, csrc, out);
    hipLaunchKernelGGL(k_linear1, dim3((NNODES + 255) / 256), dim3(256), 0, stream,
                       x, W1, as1, ad1, h1pre, al1, ar1);
    hipLaunchKernelGGL(k_agg1,    dim3(NNODES / 4), dim3(256), 0, stream,
                       h1pre, al1, ar1, rowptr, csrc, b1, h1);
    hipLaunchKernelGGL(k_linear2, dim3(NNODES / 4), dim3(256), 0, stream,
                       h1, W2, as2, ad2, h2pre, al2, ar2);
    hipLaunchKernelGGL(k_agg2,    dim3(NNODES), dim3(256), 0, stream,
                       h2pre, al2, ar2, rowptr, csrc, b2, h2);
    hipLaunchKernelGGL(k_gemm_sig, dim3(GTRI), dim3(512), 0, stream, h2, out);
}